// Round 2
// baseline (346.810 us; speedup 1.0000x reference)
//
#include <hip/hip_runtime.h>

constexpr int   T   = 4096;
constexpr float VTH = 1.27f;
constexpr int   NC  = T / 4;   // float4 chunks per row
constexpr int   P   = 8;       // chunks per prefetch block
constexpr int   NB  = NC / P;  // prefetch blocks

// One LIF step. Produces outputs for step t (vo, so) and finalizes dv[t-1] (dvo).
// State: v (membrane; 0 carried out of a spike step — the counter==1 reset folded in),
// u (countdown: 7 right after a spike at t>=1, decrements to 0).
//   x zeroed this step  iff u_entry >= 3   (== reference z>0)
//   dv[t-1] zeroed      iff u_exit  >  0   (== spike at t' in [t-7 .. t], i.e. col t-1 in [t'-1, t'+6-1])
__device__ __forceinline__ bool lif_step(float x, float decay, float& v, float& u,
                                         float& vo, float& so, float& dvo, float xprev,
                                         bool setu) {
    float t1 = __fmul_rn(decay, v);        // decay*(v - V_REST), V_REST=0
    float vd = __fsub_rn(v, t1);           // unfused — matches reference rounding
    float xe = (u >= 3.0f) ? 0.0f : x;
    float vn = __fadd_rn(vd, xe);
    bool  s  = vn > VTH;
    vo = s ? VTH  : vn;
    so = s ? 1.0f : 0.0f;
    v  = s ? 0.0f : vn;
    float us = (setu && s) ? 8.0f : u;     // t=0 spike does NOT arm the window
    u = fmaxf(us - 1.0f, 0.0f);
    dvo = (u > 0.0f) ? 0.0f : xprev;
    return s;
}

// Normal chunk c (c >= 1): 4 steps; first step completes dv chunk c-1.
__device__ __forceinline__ void chunk_norm(int c, float4 X, float decay,
        float& v, float& u, float& xprev, float4& dvb,
        float4* __restrict__ v4, float4* __restrict__ s4, float4* __restrict__ d4) {
    float4 vo, so;
    lif_step(X.x, decay, v, u, vo.x, so.x, dvb.w, xprev, true); xprev = X.x;
    d4[c - 1] = dvb;                       // dv[4c-4 .. 4c-1] complete
    lif_step(X.y, decay, v, u, vo.y, so.y, dvb.x, xprev, true); xprev = X.y;
    lif_step(X.z, decay, v, u, vo.z, so.z, dvb.y, xprev, true); xprev = X.z;
    lif_step(X.w, decay, v, u, vo.w, so.w, dvb.z, xprev, true); xprev = X.w;
    v4[c] = vo; s4[c] = so;
}

__global__ __launch_bounds__(64, 1)
void lif_scan(const float* __restrict__ ode, const float* __restrict__ decay_p,
              float* __restrict__ vout, float* __restrict__ sout,
              float* __restrict__ dvout) {
    const int b = blockIdx.x * 64 + threadIdx.x;
    const float decay = decay_p[0];

    const size_t bt = (size_t)b * T;
    const float4* __restrict__ x4 = (const float4*)(ode + bt);
    float4* __restrict__ v4 = (float4*)(vout + bt);
    float4* __restrict__ s4 = (float4*)(sout + bt);
    float4* __restrict__ d4 = (float4*)(dvout + bt);

    float v = 0.0f, u = 0.0f, xprev = 0.0f, dvd;
    float4 dvb;

    float4 cur[P], nxt[P];
    #pragma unroll
    for (int i = 0; i < P; ++i) cur[i] = x4[i];

    // ---- block 0: prefetch block 1, then chunk 0 (special) + chunks 1..P-1
    #pragma unroll
    for (int i = 0; i < P; ++i) nxt[i] = x4[P + i];
    {
        float4 X = cur[0]; float4 vo, so;
        bool s0 = lif_step(X.x, decay, v, u, vo.x, so.x, dvd,   xprev, false); xprev = X.x;
        bool s1 = lif_step(X.y, decay, v, u, vo.y, so.y, dvb.x, xprev, true ); xprev = X.y;
        lif_step(X.z, decay, v, u, vo.z, so.z, dvb.y, xprev, true); xprev = X.z;
        lif_step(X.w, decay, v, u, vo.w, so.w, dvb.z, xprev, true); xprev = X.w;
        if (s0 && s1) vo.z = VTH;          // counter==2 corner: spikes at t=0 and t=1 force v_rec[2]=VTH
        v4[0] = vo; s4[0] = so;
    }
    #pragma unroll
    for (int i = 1; i < P; ++i)
        chunk_norm(i, cur[i], decay, v, u, xprev, dvb, v4, s4, d4);
    #pragma unroll
    for (int i = 0; i < P; ++i) cur[i] = nxt[i];

    // ---- blocks 1..NB-1 (chunk c consumes cur[i] == x4[blk*P + i] — indices now aligned)
    for (int blk = 1; blk < NB; ++blk) {
        const int base = blk * P;
        if (blk + 1 < NB) {
            #pragma unroll
            for (int i = 0; i < P; ++i) nxt[i] = x4[base + P + i];
        }
        #pragma unroll
        for (int i = 0; i < P; ++i)
            chunk_norm(base + i, cur[i], decay, v, u, xprev, dvb, v4, s4, d4);
        #pragma unroll
        for (int i = 0; i < P; ++i) cur[i] = nxt[i];
    }

    // dv[T-1]: zero iff last spike >= T-6  <=>  u > 1 after the final step
    dvb.w = (u > 1.0f) ? 0.0f : xprev;
    d4[NC - 1] = dvb;
}

extern "C" void kernel_launch(void* const* d_in, const int* in_sizes, int n_in,
                              void* d_out, int out_size, void* d_ws, size_t ws_size,
                              hipStream_t stream) {
    const float* ode   = (const float*)d_in[0];
    const float* decay = (const float*)d_in[1];
    float* out = (float*)d_out;

    const int BT = in_sizes[0];      // B*T*1
    const int B  = BT / T;           // 2048

    float* vout  = out;
    float* sout  = out + (size_t)BT;
    float* dvout = out + 2 * (size_t)BT;

    dim3 block(64);
    dim3 grid(B / 64);               // 32 blocks × 1 wave, spread across CUs
    lif_scan<<<grid, block, 0, stream>>>(ode, decay, vout, sout, dvout);
}